// Round 6
// baseline (130.238 us; speedup 1.0000x reference)
//
#include <hip/hip_runtime.h>
#include <hip/hip_bf16.h>
#include <cstdint>

// N=2, L=2048, H=8, d=64, D=512. Inputs/outputs f32; features bf16 + MFMA.

typedef __bf16 bf16x8 __attribute__((ext_vector_type(8)));
typedef float f32x16 __attribute__((ext_vector_type(16)));
typedef unsigned short u16x8 __attribute__((ext_vector_type(8)));
typedef uint32_t u32x4 __attribute__((ext_vector_type(4)));

__device__ __forceinline__ unsigned short f2bfu(float f) {
    uint32_t u = __float_as_uint(f);
    uint32_t r = (u + 0x7fffu + ((u >> 16) & 1u)) >> 16;
    return (unsigned short)r;
}
__device__ __forceinline__ uint32_t cvt2(float a, float b) {
    __hip_bfloat162 h = __float22bfloat162_rn(make_float2(a, b));
    return *reinterpret_cast<uint32_t*>(&h);
}
__device__ __forceinline__ float softplusf(float x) {
    return fmaxf(x, 0.f) + __logf(1.f + __expf(-fabsf(x)));
}
// pack two f32 -> one u32 of 2 bf16 (src0 -> low half)
__device__ __forceinline__ uint32_t pkbf(float a, float b) {
    uint32_t d;
    asm("v_cvt_pk_bf16_f32 %0, %1, %2" : "=v"(d) : "v"(a), "v"(b));
    return d;
}
// v_permlane32_swap_b32: a[l>=32] <-> b[l-32]
__device__ __forceinline__ void plswap(uint32_t& a, uint32_t& b) {
    asm volatile("v_permlane32_swap_b32 %0, %1" : "+v"(a), "+v"(b));
}

// ---------------------------------------------------------------------------
// cvt: one-shot f32 -> bf16 of query/key/Wq/Wk/Wv. UNCHANGED (passed r3-r5).
// ---------------------------------------------------------------------------
__global__ __launch_bounds__(256) void cvt_kernel(
    const float* __restrict__ query, const float* __restrict__ key,
    const float* __restrict__ Wq, const float* __restrict__ Wk,
    const float* __restrict__ Wv,
    unsigned short* __restrict__ Xqb, unsigned short* __restrict__ Xkb,
    unsigned short* __restrict__ Wqb, unsigned short* __restrict__ Wkb,
    unsigned short* __restrict__ Wvb)
{
    const int z = blockIdx.z;
    const float* src;
    unsigned short* dst;
    int n8;
    if (z == 0)      { src = query; dst = Xqb; n8 = 4096 * 512 / 8; }
    else if (z == 1) { src = key;   dst = Xkb; n8 = 4096 * 512 / 8; }
    else if (z == 2) { src = Wq;    dst = Wqb; n8 = 512 * 512 / 8;  }
    else if (z == 3) { src = Wk;    dst = Wkb; n8 = 512 * 512 / 8;  }
    else             { src = Wv;    dst = Wvb; n8 = 512 * 512 / 8;  }
    int idx = blockIdx.x * 256 + threadIdx.x;
    if (idx >= n8) return;
    const float4* s = (const float4*)src + (size_t)idx * 2;
    float4 a = s[0], b = s[1];
    uint4 o;
    o.x = cvt2(a.x, a.y); o.y = cvt2(a.z, a.w);
    o.z = cvt2(b.x, b.y); o.w = cvt2(b.z, b.w);
    *(uint4*)&dst[(size_t)idx * 8] = o;
}

// ---------------------------------------------------------------------------
// proj v3: 128x64 tiles, 768 blocks (3/CU). UNCHANGED from round 5
// (~34 us; kept byte-identical so this round's delta attributes to attn).
// ---------------------------------------------------------------------------
__global__ __launch_bounds__(256) void proj_kernel(
    const unsigned short* __restrict__ Xqb, const unsigned short* __restrict__ Xkb,
    const unsigned short* __restrict__ Wqb, const unsigned short* __restrict__ Wkb,
    const unsigned short* __restrict__ Wvb, const float* __restrict__ coef,
    const float* __restrict__ posw, const float* __restrict__ posb,
    unsigned short* __restrict__ Af, unsigned short* __restrict__ Bf,
    unsigned short* __restrict__ Vf)
{
    const int mode = blockIdx.z;
    const int c0 = blockIdx.x * 64;    // 8 tiles
    const int m0 = blockIdx.y * 128;   // 32 tiles
    const unsigned short* X = (mode == 0) ? Xqb : Xkb;
    const unsigned short* W = (mode == 0) ? Wqb : (mode == 1 ? Wkb : Wvb);

    __shared__ __align__(16) char smem[(128 + 64) * 72 * 2];  // 27648 B
    unsigned short* Xs = (unsigned short*)smem;                   // [128][72]
    unsigned short* Ws = (unsigned short*)(smem + 128 * 72 * 2);  // [64][72]

    const int t = threadIdx.x;
    const int lane = t & 63, wv = t >> 6;
    const int lm = lane & 31, half = lane >> 5;
    const int wrow = wv >> 1, wcol = wv & 1;

    f32x16 acc[2] = {};

    u16x8 px[4], pw[2];
    {
#pragma unroll
        for (int it = 0; it < 4; ++it) {
            int cid = t + it * 256, row = cid >> 3, seg = cid & 7;
            px[it] = *(const u16x8*)&X[(size_t)(m0 + row) * 512 + seg * 8];
        }
#pragma unroll
        for (int it = 0; it < 2; ++it) {
            int cid = t + it * 256, row = cid >> 3, seg = cid & 7;
            pw[it] = *(const u16x8*)&W[(size_t)(c0 + row) * 512 + seg * 8];
        }
    }

    for (int kt = 0; kt < 8; ++kt) {
        __syncthreads();
#pragma unroll
        for (int it = 0; it < 4; ++it) {
            int cid = t + it * 256, row = cid >> 3, seg = cid & 7;
            *(u16x8*)&Xs[row * 72 + seg * 8] = px[it];
        }
#pragma unroll
        for (int it = 0; it < 2; ++it) {
            int cid = t + it * 256, row = cid >> 3, seg = cid & 7;
            *(u16x8*)&Ws[row * 72 + seg * 8] = pw[it];
        }
        __syncthreads();
        if (kt < 7) {
            int ko = (kt + 1) * 64;
#pragma unroll
            for (int it = 0; it < 4; ++it) {
                int cid = t + it * 256, row = cid >> 3, seg = cid & 7;
                px[it] = *(const u16x8*)&X[(size_t)(m0 + row) * 512 + ko + seg * 8];
            }
#pragma unroll
            for (int it = 0; it < 2; ++it) {
                int cid = t + it * 256, row = cid >> 3, seg = cid & 7;
                pw[it] = *(const u16x8*)&W[(size_t)(c0 + row) * 512 + ko + seg * 8];
            }
        }
        const unsigned short* ab = &Xs[(64 * wrow + lm) * 72 + half * 8];
        const unsigned short* bb = &Ws[(32 * wcol + lm) * 72 + half * 8];
        __builtin_amdgcn_s_setprio(1);
#pragma unroll
        for (int ks = 0; ks < 4; ++ks) {
            bf16x8 a0 = *(const bf16x8*)(ab + ks * 16);
            bf16x8 a1 = *(const bf16x8*)(ab + 32 * 72 + ks * 16);
            bf16x8 b  = *(const bf16x8*)(bb + ks * 16);
            acc[0] = __builtin_amdgcn_mfma_f32_32x32x16_bf16(a0, b, acc[0], 0, 0, 0);
            acc[1] = __builtin_amdgcn_mfma_f32_32x32x16_bf16(a1, b, acc[1], 0, 0, 0);
        }
        __builtin_amdgcn_s_setprio(0);
    }

    if (mode != 2) {
        unsigned short* Feat = (mode == 0) ? Af : Bf;
        int c = c0 + 32 * wcol + lm;
        int h = c >> 6, jj = c & 63;
        float wgt = posw[c];
        float bia = (mode == 0) ? posb[c] : 0.f;
        float cf  = (mode == 1) ? coef[c] : 1.f;
#pragma unroll
        for (int i = 0; i < 2; ++i)
#pragma unroll
        for (int r = 0; r < 16; ++r) {
            int rl = (r & 3) + 8 * (r >> 2) + 4 * half;
            int m = m0 + 64 * wrow + 32 * i + rl;
            int n = m >> 11, l = m & 2047;
            float ang = (float)l * wgt + bia;
            float sn, cs; __sincosf(ang, &sn, &cs);
            float v = softplusf(acc[i][r]) * cf;
            size_t base = ((size_t)(n * 8 + h) * 2048 + l) * 128 + jj;
            Feat[base]      = f2bfu(v * cs);
            Feat[base + 64] = f2bfu(v * sn);
        }
    } else {
        float* tb = (float*)smem;
        float* tbw = tb + wv * (32 * 34);
        __syncthreads();
#pragma unroll
        for (int i = 0; i < 2; ++i) {
#pragma unroll
            for (int r = 0; r < 16; ++r) {
                int rl = (r & 3) + 8 * (r >> 2) + 4 * half;
                tbw[lm * 34 + rl] = acc[i][r];
            }
            int mb = m0 + 64 * wrow + 32 * i;
            int n = mb >> 11, l0 = mb & 2047;
#pragma unroll
            for (int rep = 0; rep < 16; ++rep) {
                int cl = rep * 2 + half;
                float v = tbw[cl * 34 + lm];
                int c = c0 + 32 * wcol + cl;
                int h = c >> 6, dd = c & 63;
                Vf[((size_t)(n * 8 + h) * 64 + dd) * 2048 + l0 + lm] = f2bfu(v);
            }
        }
    }
}

// ---------------------------------------------------------------------------
// attn v3: targets the measured ~3000 cy/tile serial cost (r2 split-k null +
// r5 budget => not wave-count-bound). Changes vs v2:
//  1. LDS double-buffer (Bs[2]/Vs[2]) -> ONE barrier per k-tile (was 2).
//     Writes go to the buffer not being read; the single post-write barrier
//     gives visibility, and WAR is safe (buf-c reads finish before barrier
//     kt+1, next buf-c write is after it).
//  2. QK split into two independent 4-deep MFMA chains (halves exposed
//     dependent latency). No launch-bounds cap -> no r1-style spill.
//  3. Longest-first ordering: qq = 31 - (bx>>4); the 32-tile blocks launch
//     first instead of forming a serial tail (explains the r2 null).
// ---------------------------------------------------------------------------
__global__ __launch_bounds__(256) void attn_kernel(
    const unsigned short* __restrict__ Af, const unsigned short* __restrict__ Bf,
    const unsigned short* __restrict__ Vf, float* __restrict__ out)
{
    const int bx = blockIdx.x;
    const int nh = bx & 15;
    const int qq = 31 - (bx >> 4);   // longest blocks first
    const int q0 = qq * 64;

    __shared__ unsigned short Bs[2][64 * 136];   // K-features dbuf; Q-stage at init; O-merge overlay at end
    __shared__ unsigned short Vs[2][64 * 72];    // V [dd][k] dbuf
    __shared__ float zf[64];

    const int t = threadIdx.x;
    const int lane = t & 63, wv = t >> 6;
    const int lm = lane & 31, half = lane >> 5;
    const int qb = wv >> 1, kb = wv & 1;
    const int n = nh >> 3, h = nh & 7;

    const unsigned short* Ah = Af + (size_t)nh * 2048 * 128;
    const unsigned short* Bh = Bf + (size_t)nh * 2048 * 128;
    const unsigned short* Vh = Vf + (size_t)nh * 64 * 2048;

    // stage Q rows through Bs[0] once; pull Q-fragments to regs
#pragma unroll
    for (int it = 0; it < 4; ++it) {
        int cid = t + it * 256, row = cid >> 4, off = (cid & 15) << 3;
        *(u16x8*)&Bs[0][row * 136 + off] = *(const u16x8*)&Ah[(size_t)(q0 + row) * 128 + off];
    }
    if (t < 64) zf[t] = 0.f;
    __syncthreads();
    bf16x8 qfrag[8];
    {
        const unsigned short* ab = &Bs[0][(32 * qb + lm) * 136 + half * 8];
#pragma unroll
        for (int c = 0; c < 8; ++c) qfrag[c] = *(const bf16x8*)(ab + c * 16);
    }
    __syncthreads();   // all qfrag reads of Bs[0] done before tile-0 writes it

    f32x16 oacc0 = {}, oacc1 = {};
    float zsum = 0.f;

    u16x8 pb[4], pv[2];
#pragma unroll
    for (int it = 0; it < 4; ++it) {
        int cid = t + it * 256, row = cid >> 4, off = (cid & 15) << 3;
        pb[it] = *(const u16x8*)&Bh[(size_t)row * 128 + off];
    }
#pragma unroll
    for (int it = 0; it < 2; ++it) {
        int cid = t + it * 256, row = cid >> 3, off = (cid & 7) << 3;
        pv[it] = *(const u16x8*)&Vh[(size_t)row * 2048 + off];
    }

    int c = 0;
    for (int kt = 0; kt <= qq; ++kt) {
        unsigned short* bsc = Bs[c];
        unsigned short* vsc = Vs[c];
        // write staged tile kt into buffer c (not being read by anyone)
#pragma unroll
        for (int it = 0; it < 4; ++it) {
            int cid = t + it * 256, row = cid >> 4, off = (cid & 15) << 3;
            *(u16x8*)&bsc[row * 136 + off] = pb[it];
        }
#pragma unroll
        for (int it = 0; it < 2; ++it) {
            int cid = t + it * 256, row = cid >> 3, off = (cid & 7) << 3;
            *(u16x8*)&vsc[row * 72 + off] = pv[it];
        }
        // prefetch tile kt+1 into regs
        if (kt < qq) {
            int k1 = (kt + 1) * 64;
#pragma unroll
            for (int it = 0; it < 4; ++it) {
                int cid = t + it * 256, row = cid >> 4, off = (cid & 15) << 3;
                pb[it] = *(const u16x8*)&Bh[(size_t)(k1 + row) * 128 + off];
            }
#pragma unroll
            for (int it = 0; it < 2; ++it) {
                int cid = t + it * 256, row = cid >> 3, off = (cid & 7) << 3;
                pv[it] = *(const u16x8*)&Vh[(size_t)row * 2048 + k1 + off];
            }
        }
        __syncthreads();   // the ONLY barrier per tile: buffer c visible

        // S^T = K . Q^T : two independent 4-deep chains, summed after
        f32x16 sa = {}, sb = {};
        const unsigned short* kbase = &bsc[(32 * kb + lm) * 136 + half * 8];
        __builtin_amdgcn_s_setprio(1);
#pragma unroll
        for (int ks = 0; ks < 4; ++ks) {
            bf16x8 kf0 = *(const bf16x8*)(kbase + ks * 16);
            bf16x8 kf1 = *(const bf16x8*)(kbase + (ks + 4) * 16);
            sa = __builtin_amdgcn_mfma_f32_32x32x16_bf16(kf0, qfrag[ks],     sa, 0, 0, 0);
            sb = __builtin_amdgcn_mfma_f32_32x32x16_bf16(kf1, qfrag[ks + 4], sb, 0, 0, 0);
        }
        __builtin_amdgcn_s_setprio(0);
        f32x16 sacc;
#pragma unroll
        for (int r = 0; r < 16; ++r) sacc[r] = sa[r] + sb[r];

        if (kt == qq) {   // causal mask within diagonal tile
#pragma unroll
            for (int r = 0; r < 16; ++r) {
                int kl = (r & 3) + 8 * (r >> 2) + 4 * half;
                if ((32 * kb + kl) > (32 * qb + lm)) sacc[r] = 0.f;
            }
        }
#pragma unroll
        for (int r = 0; r < 16; ++r) zsum += fabsf(sacc[r]);

        union { u32x4 u; bf16x8 b; } pa0, pa1;
        {
            uint32_t A = pkbf(sacc[0], sacc[1]);
            uint32_t B = pkbf(sacc[2], sacc[3]);
            uint32_t C = pkbf(sacc[4], sacc[5]);
            uint32_t D = pkbf(sacc[6], sacc[7]);
            plswap(A, C);
            plswap(B, D);
            pa0.u = (u32x4){A, B, C, D};
            uint32_t E = pkbf(sacc[8], sacc[9]);
            uint32_t F = pkbf(sacc[10], sacc[11]);
            uint32_t G = pkbf(sacc[12], sacc[13]);
            uint32_t H = pkbf(sacc[14], sacc[15]);
            plswap(E, G);
            plswap(F, H);
            pa1.u = (u32x4){E, F, G, H};
        }

        const unsigned short* v0 = &vsc[(size_t)lm * 72 + 32 * kb + half * 8];
        const unsigned short* v1 = &vsc[(size_t)(32 + lm) * 72 + 32 * kb + half * 8];
        __builtin_amdgcn_s_setprio(1);
        {
            bf16x8 vb00 = *(const bf16x8*)(v0);
            bf16x8 vb10 = *(const bf16x8*)(v1);
            oacc0 = __builtin_amdgcn_mfma_f32_32x32x16_bf16(pa0.b, vb00, oacc0, 0, 0, 0);
            oacc1 = __builtin_amdgcn_mfma_f32_32x32x16_bf16(pa0.b, vb10, oacc1, 0, 0, 0);
            bf16x8 vb01 = *(const bf16x8*)(v0 + 16);
            bf16x8 vb11 = *(const bf16x8*)(v1 + 16);
            oacc0 = __builtin_amdgcn_mfma_f32_32x32x16_bf16(pa1.b, vb01, oacc0, 0, 0, 0);
            oacc1 = __builtin_amdgcn_mfma_f32_32x32x16_bf16(pa1.b, vb11, oacc1, 0, 0, 0);
        }
        __builtin_amdgcn_s_setprio(0);
        c ^= 1;
    }

    atomicAdd(&zf[32 * qb + lm], zsum);
    __syncthreads();   // zf complete; all last-tile LDS reads done -> overlay safe

    float* Os = (float*)Bs;
    if (kb == 0) {
#pragma unroll
        for (int r = 0; r < 16; ++r) {
            int ql = (r & 3) + 8 * (r >> 2) + 4 * half;
            Os[(32 * qb + ql) * 65 + lm]      = oacc0[r];
            Os[(32 * qb + ql) * 65 + 32 + lm] = oacc1[r];
        }
    }
    __syncthreads();
    if (kb == 1) {
#pragma unroll
        for (int r = 0; r < 16; ++r) {
            int ql = (r & 3) + 8 * (r >> 2) + 4 * half;
            int q = q0 + 32 * qb + ql;
            float invz = 1.f / zf[32 * qb + ql];
            float o0 = (Os[(32 * qb + ql) * 65 + lm]      + oacc0[r]) * invz;
            float o1 = (Os[(32 * qb + ql) * 65 + 32 + lm] + oacc1[r]) * invz;
            size_t base = ((size_t)(n * 2048 + q)) * 512 + h * 64;
            out[base + lm]      = o0;
            out[base + 32 + lm] = o1;
        }
    }
}

extern "C" void kernel_launch(void* const* d_in, const int* in_sizes, int n_in,
                              void* d_out, int out_size, void* d_ws, size_t ws_size,
                              hipStream_t stream) {
    (void)in_sizes; (void)n_in; (void)out_size; (void)ws_size;
    const float* query = (const float*)d_in[0];
    const float* key   = (const float*)d_in[1];
    const float* Wq    = (const float*)d_in[2];
    const float* Wk    = (const float*)d_in[3];
    const float* Wv    = (const float*)d_in[4];
    const float* coef  = (const float*)d_in[5];
    const float* posw  = (const float*)d_in[6];
    const float* posb  = (const float*)d_in[7];

    unsigned short* Af  = (unsigned short*)d_ws;            // 8 MiB
    unsigned short* Bf  = Af + (size_t)16 * 2048 * 128;     // 8 MiB
    unsigned short* Vf  = Bf + (size_t)16 * 2048 * 128;     // 4 MiB
    unsigned short* Xqb = Vf + (size_t)16 * 64 * 2048;      // 4 MiB
    unsigned short* Xkb = Xqb + (size_t)4096 * 512;         // 4 MiB
    unsigned short* Wqb = Xkb + (size_t)4096 * 512;         // 0.5 MiB
    unsigned short* Wkb = Wqb + (size_t)512 * 512;          // 0.5 MiB
    unsigned short* Wvb = Wkb + (size_t)512 * 512;          // 0.5 MiB

    cvt_kernel<<<dim3(1024, 1, 5), 256, 0, stream>>>(
        query, key, Wq, Wk, Wv, Xqb, Xkb, Wqb, Wkb, Wvb);
    proj_kernel<<<dim3(8, 32, 3), 256, 0, stream>>>(
        Xqb, Xkb, Wqb, Wkb, Wvb, coef, posw, posb, Af, Bf, Vf);
    attn_kernel<<<dim3(512), 256, 0, stream>>>(
        Af, Bf, Vf, (float*)d_out);
}

// Round 8
// 129.966 us; speedup vs baseline: 1.0021x; 1.0021x over previous
//
#include <hip/hip_runtime.h>
#include <hip/hip_bf16.h>
#include <cstdint>

// N=2, L=2048, H=8, d=64, D=512. Inputs/outputs f32; features bf16 + MFMA.

typedef __bf16 bf16x8 __attribute__((ext_vector_type(8)));
typedef float f32x16 __attribute__((ext_vector_type(16)));
typedef unsigned short u16x8 __attribute__((ext_vector_type(8)));
typedef uint32_t u32x4 __attribute__((ext_vector_type(4)));

__device__ __forceinline__ unsigned short f2bfu(float f) {
    uint32_t u = __float_as_uint(f);
    uint32_t r = (u + 0x7fffu + ((u >> 16) & 1u)) >> 16;
    return (unsigned short)r;
}
__device__ __forceinline__ uint32_t cvt2(float a, float b) {
    __hip_bfloat162 h = __float22bfloat162_rn(make_float2(a, b));
    return *reinterpret_cast<uint32_t*>(&h);
}
__device__ __forceinline__ float softplusf(float x) {
    return fmaxf(x, 0.f) + __logf(1.f + __expf(-fabsf(x)));
}
// pack two f32 -> one u32 of 2 bf16 (src0 -> low half)
__device__ __forceinline__ uint32_t pkbf(float a, float b) {
    uint32_t d;
    asm("v_cvt_pk_bf16_f32 %0, %1, %2" : "=v"(d) : "v"(a), "v"(b));
    return d;
}
// v_permlane32_swap_b32: a[l>=32] <-> b[l-32]
__device__ __forceinline__ void plswap(uint32_t& a, uint32_t& b) {
    asm volatile("v_permlane32_swap_b32 %0, %1" : "+v"(a), "+v"(b));
}
// async global->LDS, 16B per lane; dest is wave-uniform base + lane*16
__device__ __forceinline__ void gload16(const unsigned short* g, unsigned short* l) {
    __builtin_amdgcn_global_load_lds(
        (const __attribute__((address_space(1))) unsigned int*)g,
        (__attribute__((address_space(3))) unsigned int*)l, 16, 0, 0);
}

// ---------------------------------------------------------------------------
// cvt: one-shot f32 -> bf16 of query/key/Wq/Wk/Wv. UNCHANGED (passed r3-r6).
// ---------------------------------------------------------------------------
__global__ __launch_bounds__(256) void cvt_kernel(
    const float* __restrict__ query, const float* __restrict__ key,
    const float* __restrict__ Wq, const float* __restrict__ Wk,
    const float* __restrict__ Wv,
    unsigned short* __restrict__ Xqb, unsigned short* __restrict__ Xkb,
    unsigned short* __restrict__ Wqb, unsigned short* __restrict__ Wkb,
    unsigned short* __restrict__ Wvb)
{
    const int z = blockIdx.z;
    const float* src;
    unsigned short* dst;
    int n8;
    if (z == 0)      { src = query; dst = Xqb; n8 = 4096 * 512 / 8; }
    else if (z == 1) { src = key;   dst = Xkb; n8 = 4096 * 512 / 8; }
    else if (z == 2) { src = Wq;    dst = Wqb; n8 = 512 * 512 / 8;  }
    else if (z == 3) { src = Wk;    dst = Wkb; n8 = 512 * 512 / 8;  }
    else             { src = Wv;    dst = Wvb; n8 = 512 * 512 / 8;  }
    int idx = blockIdx.x * 256 + threadIdx.x;
    if (idx >= n8) return;
    const float4* s = (const float4*)src + (size_t)idx * 2;
    float4 a = s[0], b = s[1];
    uint4 o;
    o.x = cvt2(a.x, a.y); o.y = cvt2(a.z, a.w);
    o.z = cvt2(b.x, b.y); o.w = cvt2(b.z, b.w);
    *(uint4*)&dst[(size_t)idx * 8] = o;
}

// ---------------------------------------------------------------------------
// proj v4 (r7 compile-fix of the r6 design): 128x64 tiles, 768 blocks (3/CU);
// K-loop rebuilt around async staging (T3-minimum + m193 + rule #21):
//  - global_load_lds (16B) stages directly into LINEAR LDS — no VGPR
//    round-trip, no ds_write issue.
//  - raw s_barrier + counted `s_waitcnt vmcnt(6)`: next tile's 6 DMA ops
//    stay in flight ACROSS the barriers and land under this tile's MFMA
//    (__syncthreads would drain vmcnt(0) and expose full L3 latency/phase —
//     the hypothesized cause of proj's unexplained ~33 us).
//  - T2 swizzle: inverse-XOR on the global source + XOR on the LDS read.
// LDS pointers computed by offset arithmetic (NO local pointer arrays —
// r7's addrspacecast static-initializer compile error).
// ---------------------------------------------------------------------------
#define XTILE (128 * 64)
#define WTILE (64 * 64)

__global__ __launch_bounds__(256) void proj_kernel(
    const unsigned short* __restrict__ Xqb, const unsigned short* __restrict__ Xkb,
    const unsigned short* __restrict__ Wqb, const unsigned short* __restrict__ Wkb,
    const unsigned short* __restrict__ Wvb, const float* __restrict__ coef,
    const float* __restrict__ posw, const float* __restrict__ posb,
    unsigned short* __restrict__ Af, unsigned short* __restrict__ Bf,
    unsigned short* __restrict__ Vf)
{
    const int mode = blockIdx.z;
    const int c0 = blockIdx.x * 64;    // 8 tiles
    const int m0 = blockIdx.y * 128;   // 32 tiles
    const unsigned short* X = (mode == 0) ? Xqb : Xkb;
    const unsigned short* W = (mode == 0) ? Wqb : (mode == 1 ? Wkb : Wvb);

    // dbuf linear tiles: X buf b at smem + b*XTILE; W buf b at smem + 2*XTILE + b*WTILE
    __shared__ __align__(16) unsigned short smem[2 * XTILE + 2 * WTILE];  // 48 KB

    const int t = threadIdx.x;
    const int lane = t & 63, wv = t >> 6;
    const int lm = lane & 31, half = lane >> 5;
    const int wrow = wv >> 1, wcol = wv & 1;

    f32x16 acc[2] = {};

    // stage tile kt into buffer b: 4 X-chunks + 2 W-chunks per thread,
    // global source pre-swizzled (seg ^ row&7) so linear LDS dest lands
    // in swizzled layout; 6 vmem ops per wave per stage.
    auto stage = [&](int kt, int b) {
        int ko = kt * 64;
        unsigned short* xd = smem + b * XTILE;
        unsigned short* wd = smem + 2 * XTILE + b * WTILE;
#pragma unroll
        for (int it = 0; it < 4; ++it) {
            int cid = t + it * 256, row = cid >> 3, seg = cid & 7;
            const unsigned short* src =
                X + (size_t)(m0 + row) * 512 + ko + (((seg ^ (row & 7)) << 3));
            gload16(src, xd + cid * 8);
        }
#pragma unroll
        for (int it = 0; it < 2; ++it) {
            int cid = t + it * 256, row = cid >> 3, seg = cid & 7;
            const unsigned short* src =
                W + (size_t)(c0 + row) * 512 + ko + (((seg ^ (row & 7)) << 3));
            gload16(src, wd + cid * 8);
        }
    };

    stage(0, 0);
    const int rx = 64 * wrow + lm, rw = 32 * wcol + lm;
    for (int kt = 0; kt < 8; ++kt) {
        if (kt < 7) {
            stage(kt + 1, (kt + 1) & 1);
            asm volatile("s_waitcnt vmcnt(6)" ::: "memory");   // tile kt landed
        } else {
            asm volatile("s_waitcnt vmcnt(0)" ::: "memory");
        }
        __builtin_amdgcn_s_barrier();      // all waves' tile-kt DMA visible

        const unsigned short* xb = smem + (kt & 1) * XTILE;
        const unsigned short* wb = smem + 2 * XTILE + (kt & 1) * WTILE;
        __builtin_amdgcn_s_setprio(1);
#pragma unroll
        for (int ks = 0; ks < 4; ++ks) {
            int sA = (((half + 2 * ks) ^ (lm & 7)) << 3);
            bf16x8 a0 = *(const bf16x8*)&xb[rx * 64 + sA];
            bf16x8 a1 = *(const bf16x8*)&xb[(rx + 32) * 64 + sA];
            bf16x8 b  = *(const bf16x8*)&wb[rw * 64 + sA];
            acc[0] = __builtin_amdgcn_mfma_f32_32x32x16_bf16(a0, b, acc[0], 0, 0, 0);
            acc[1] = __builtin_amdgcn_mfma_f32_32x32x16_bf16(a1, b, acc[1], 0, 0, 0);
        }
        __builtin_amdgcn_s_setprio(0);
        asm volatile("s_waitcnt lgkmcnt(0)" ::: "memory");   // reads done before
        __builtin_amdgcn_sched_barrier(0);                   // next-iter DMA WAR
        __builtin_amdgcn_s_barrier();
    }

    if (mode != 2) {
        unsigned short* Feat = (mode == 0) ? Af : Bf;
        int c = c0 + 32 * wcol + lm;
        int h = c >> 6, jj = c & 63;
        float wgt = posw[c];
        float bia = (mode == 0) ? posb[c] : 0.f;
        float cf  = (mode == 1) ? coef[c] : 1.f;
#pragma unroll
        for (int i = 0; i < 2; ++i)
#pragma unroll
        for (int r = 0; r < 16; ++r) {
            int rl = (r & 3) + 8 * (r >> 2) + 4 * half;
            int m = m0 + 64 * wrow + 32 * i + rl;
            int n = m >> 11, l = m & 2047;
            float ang = (float)l * wgt + bia;
            float sn, cs; __sincosf(ang, &sn, &cs);
            float v = softplusf(acc[i][r]) * cf;
            size_t base = ((size_t)(n * 8 + h) * 2048 + l) * 128 + jj;
            Feat[base]      = f2bfu(v * cs);
            Feat[base + 64] = f2bfu(v * sn);
        }
    } else {
        // transpose through LDS; per-wave private 32x34 f32 buffer overlays
        // smem (17408 B <= 48 KB). Loop's final barrier already ordered all
        // LDS reads; one sync before overlay reuse.
        float* tb = (float*)smem;
        float* tbw = tb + wv * (32 * 34);
        __syncthreads();
#pragma unroll
        for (int i = 0; i < 2; ++i) {
#pragma unroll
            for (int r = 0; r < 16; ++r) {
                int rl = (r & 3) + 8 * (r >> 2) + 4 * half;
                tbw[lm * 34 + rl] = acc[i][r];
            }
            int mb = m0 + 64 * wrow + 32 * i;
            int n = mb >> 11, l0 = mb & 2047;
#pragma unroll
            for (int rep = 0; rep < 16; ++rep) {
                int cl = rep * 2 + half;
                float v = tbw[cl * 34 + lm];
                int c = c0 + 32 * wcol + cl;
                int h = c >> 6, dd = c & 63;
                Vf[((size_t)(n * 8 + h) * 64 + dd) * 2048 + l0 + lm] = f2bfu(v);
            }
        }
    }
}

// ---------------------------------------------------------------------------
// attn v2 (r5 version, reverted from r6's null v3): swapped QK^T (T12),
// in-register P via cvt_pk+permlane32_swap, complementary block pairing.
// ---------------------------------------------------------------------------
__global__ __launch_bounds__(256) void attn_kernel(
    const unsigned short* __restrict__ Af, const unsigned short* __restrict__ Bf,
    const unsigned short* __restrict__ Vf, float* __restrict__ out)
{
    const int bx = blockIdx.x;
    const int nh = bx & 15;
    const int p  = bx >> 4;
    const int qq = (p < 16) ? p : 47 - p;   // bx and bx+256 complementary
    const int q0 = qq * 64;

    __shared__ unsigned short Bs[64 * 136];   // K-features; Q-stage at init; O-merge overlay at end
    __shared__ unsigned short Vs[64 * 72];    // V [dd][k]
    __shared__ float zf[64];

    const int t = threadIdx.x;
    const int lane = t & 63, wv = t >> 6;
    const int lm = lane & 31, half = lane >> 5;
    const int qb = wv >> 1, kb = wv & 1;
    const int n = nh >> 3, h = nh & 7;

    const unsigned short* Ah = Af + (size_t)nh * 2048 * 128;
    const unsigned short* Bh = Bf + (size_t)nh * 2048 * 128;
    const unsigned short* Vh = Vf + (size_t)nh * 64 * 2048;

#pragma unroll
    for (int it = 0; it < 4; ++it) {
        int cid = t + it * 256, row = cid >> 4, off = (cid & 15) << 3;
        *(u16x8*)&Bs[row * 136 + off] = *(const u16x8*)&Ah[(size_t)(q0 + row) * 128 + off];
    }
    if (t < 64) zf[t] = 0.f;
    __syncthreads();
    bf16x8 qfrag[8];
    {
        const unsigned short* ab = &Bs[(32 * qb + lm) * 136 + half * 8];
#pragma unroll
        for (int c = 0; c < 8; ++c) qfrag[c] = *(const bf16x8*)(ab + c * 16);
    }

    f32x16 oacc0 = {}, oacc1 = {};
    float zsum = 0.f;

    u16x8 pb[4], pv[2];
#pragma unroll
    for (int it = 0; it < 4; ++it) {
        int cid = t + it * 256, row = cid >> 4, off = (cid & 15) << 3;
        pb[it] = *(const u16x8*)&Bh[(size_t)row * 128 + off];
    }
#pragma unroll
    for (int it = 0; it < 2; ++it) {
        int cid = t + it * 256, row = cid >> 3, off = (cid & 7) << 3;
        pv[it] = *(const u16x8*)&Vh[(size_t)row * 2048 + off];
    }

    for (int kt = 0; kt <= qq; ++kt) {
        __syncthreads();
#pragma unroll
        for (int it = 0; it < 4; ++it) {
            int cid = t + it * 256, row = cid >> 4, off = (cid & 15) << 3;
            *(u16x8*)&Bs[row * 136 + off] = pb[it];
        }
#pragma unroll
        for (int it = 0; it < 2; ++it) {
            int cid = t + it * 256, row = cid >> 3, off = (cid & 7) << 3;
            *(u16x8*)&Vs[row * 72 + off] = pv[it];
        }
        __syncthreads();
        if (kt < qq) {
            int k1 = (kt + 1) * 64;
#pragma unroll
            for (int it = 0; it < 4; ++it) {
                int cid = t + it * 256, row = cid >> 4, off = (cid & 15) << 3;
                pb[it] = *(const u16x8*)&Bh[(size_t)(k1 + row) * 128 + off];
            }
#pragma unroll
            for (int it = 0; it < 2; ++it) {
                int cid = t + it * 256, row = cid >> 3, off = (cid & 7) << 3;
                pv[it] = *(const u16x8*)&Vh[(size_t)row * 2048 + k1 + off];
            }
        }

        f32x16 sacc = {};
        const unsigned short* kbase = &Bs[(32 * kb + lm) * 136 + half * 8];
        __builtin_amdgcn_s_setprio(1);
#pragma unroll
        for (int ks = 0; ks < 8; ++ks) {
            bf16x8 kf = *(const bf16x8*)(kbase + ks * 16);
            sacc = __builtin_amdgcn_mfma_f32_32x32x16_bf16(kf, qfrag[ks], sacc, 0, 0, 0);
        }
        __builtin_amdgcn_s_setprio(0);

        if (kt == qq) {
#pragma unroll
            for (int r = 0; r < 16; ++r) {
                int kl = (r & 3) + 8 * (r >> 2) + 4 * half;
                if ((32 * kb + kl) > (32 * qb + lm)) sacc[r] = 0.f;
            }
        }
#pragma unroll
        for (int r = 0; r < 16; ++r) zsum += fabsf(sacc[r]);

        union { u32x4 u; bf16x8 b; } pa0, pa1;
        {
            uint32_t A = pkbf(sacc[0], sacc[1]);
            uint32_t B = pkbf(sacc[2], sacc[3]);
            uint32_t C = pkbf(sacc[4], sacc[5]);
            uint32_t D = pkbf(sacc[6], sacc[7]);
            plswap(A, C);
            plswap(B, D);
            pa0.u = (u32x4){A, B, C, D};
            uint32_t E = pkbf(sacc[8], sacc[9]);
            uint32_t F = pkbf(sacc[10], sacc[11]);
            uint32_t G = pkbf(sacc[12], sacc[13]);
            uint32_t H = pkbf(sacc[14], sacc[15]);
            plswap(E, G);
            plswap(F, H);
            pa1.u = (u32x4){E, F, G, H};
        }

        const unsigned short* v0 = &Vs[(size_t)lm * 72 + 32 * kb + half * 8];
        const unsigned short* v1 = &Vs[(size_t)(32 + lm) * 72 + 32 * kb + half * 8];
        __builtin_amdgcn_s_setprio(1);
        {
            bf16x8 vb00 = *(const bf16x8*)(v0);
            bf16x8 vb10 = *(const bf16x8*)(v1);
            oacc0 = __builtin_amdgcn_mfma_f32_32x32x16_bf16(pa0.b, vb00, oacc0, 0, 0, 0);
            oacc1 = __builtin_amdgcn_mfma_f32_32x32x16_bf16(pa0.b, vb10, oacc1, 0, 0, 0);
            bf16x8 vb01 = *(const bf16x8*)(v0 + 16);
            bf16x8 vb11 = *(const bf16x8*)(v1 + 16);
            oacc0 = __builtin_amdgcn_mfma_f32_32x32x16_bf16(pa1.b, vb01, oacc0, 0, 0, 0);
            oacc1 = __builtin_amdgcn_mfma_f32_32x32x16_bf16(pa1.b, vb11, oacc1, 0, 0, 0);
        }
        __builtin_amdgcn_s_setprio(0);
    }

    atomicAdd(&zf[32 * qb + lm], zsum);
    __syncthreads();

    float* Os = (float*)Bs;
    if (kb == 0) {
#pragma unroll
        for (int r = 0; r < 16; ++r) {
            int ql = (r & 3) + 8 * (r >> 2) + 4 * half;
            Os[(32 * qb + ql) * 65 + lm]      = oacc0[r];
            Os[(32 * qb + ql) * 65 + 32 + lm] = oacc1[r];
        }
    }
    __syncthreads();
    if (kb == 1) {
#pragma unroll
        for (int r = 0; r < 16; ++r) {
            int ql = (r & 3) + 8 * (r >> 2) + 4 * half;
            int q = q0 + 32 * qb + ql;
            float invz = 1.f / zf[32 * qb + ql];
            float o0 = (Os[(32 * qb + ql) * 65 + lm]      + oacc0[r]) * invz;
            float o1 = (Os[(32 * qb + ql) * 65 + 32 + lm] + oacc1[r]) * invz;
            size_t base = ((size_t)(n * 2048 + q)) * 512 + h * 64;
            out[base + lm]      = o0;
            out[base + 32 + lm] = o1;
        }
    }
}

extern "C" void kernel_launch(void* const* d_in, const int* in_sizes, int n_in,
                              void* d_out, int out_size, void* d_ws, size_t ws_size,
                              hipStream_t stream) {
    (void)in_sizes; (void)n_in; (void)out_size; (void)ws_size;
    const float* query = (const float*)d_in[0];
    const float* key   = (const float*)d_in[1];
    const float* Wq    = (const float*)d_in[2];
    const float* Wk    = (const float*)d_in[3];
    const float* Wv    = (const float*)d_in[4];
    const float* coef  = (const float*)d_in[5];
    const float* posw  = (const float*)d_in[6];
    const float* posb  = (const float*)d_in[7];

    unsigned short* Af  = (unsigned short*)d_ws;            // 8 MiB
    unsigned short* Bf  = Af + (size_t)16 * 2048 * 128;     // 8 MiB
    unsigned short* Vf  = Bf + (size_t)16 * 2048 * 128;     // 4 MiB
    unsigned short* Xqb = Vf + (size_t)16 * 64 * 2048;      // 4 MiB
    unsigned short* Xkb = Xqb + (size_t)4096 * 512;         // 4 MiB
    unsigned short* Wqb = Xkb + (size_t)4096 * 512;         // 0.5 MiB
    unsigned short* Wkb = Wqb + (size_t)512 * 512;          // 0.5 MiB
    unsigned short* Wvb = Wkb + (size_t)512 * 512;          // 0.5 MiB

    cvt_kernel<<<dim3(1024, 1, 5), 256, 0, stream>>>(
        query, key, Wq, Wk, Wv, Xqb, Xkb, Wqb, Wkb, Wvb);
    proj_kernel<<<dim3(8, 32, 3), 256, 0, stream>>>(
        Xqb, Xkb, Wqb, Wkb, Wvb, coef, posw, posb, Af, Bf, Vf);
    attn_kernel<<<dim3(512), 256, 0, stream>>>(
        Af, Bf, Vf, (float*)d_out);
}

// Round 9
// 129.085 us; speedup vs baseline: 1.0089x; 1.0068x over previous
//
#include <hip/hip_runtime.h>
#include <hip/hip_bf16.h>
#include <cstdint>

// N=2, L=2048, H=8, d=64, D=512. Inputs/outputs f32; features bf16 + MFMA.

typedef __bf16 bf16x8 __attribute__((ext_vector_type(8)));
typedef float f32x16 __attribute__((ext_vector_type(16)));
typedef unsigned short u16x8 __attribute__((ext_vector_type(8)));
typedef uint32_t u32x4 __attribute__((ext_vector_type(4)));

__device__ __forceinline__ unsigned short f2bfu(float f) {
    uint32_t u = __float_as_uint(f);
    uint32_t r = (u + 0x7fffu + ((u >> 16) & 1u)) >> 16;
    return (unsigned short)r;
}
__device__ __forceinline__ uint32_t cvt2(float a, float b) {
    __hip_bfloat162 h = __float22bfloat162_rn(make_float2(a, b));
    return *reinterpret_cast<uint32_t*>(&h);
}
__device__ __forceinline__ float softplusf(float x) {
    return fmaxf(x, 0.f) + __logf(1.f + __expf(-fabsf(x)));
}
__device__ __forceinline__ uint32_t pkbf(float a, float b) {
    uint32_t d;
    asm("v_cvt_pk_bf16_f32 %0, %1, %2" : "=v"(d) : "v"(a), "v"(b));
    return d;
}
__device__ __forceinline__ void plswap(uint32_t& a, uint32_t& b) {
    asm volatile("v_permlane32_swap_b32 %0, %1" : "+v"(a), "+v"(b));
}
__device__ __forceinline__ void gload16(const unsigned short* g, unsigned short* l) {
    __builtin_amdgcn_global_load_lds(
        (const __attribute__((address_space(1))) unsigned int*)g,
        (__attribute__((address_space(3))) unsigned int*)l, 16, 0, 0);
}

// ---------------------------------------------------------------------------
// cvt: one-shot f32 -> bf16 of query/key/Wq/Wk/Wv. UNCHANGED.
// ---------------------------------------------------------------------------
__global__ __launch_bounds__(256) void cvt_kernel(
    const float* __restrict__ query, const float* __restrict__ key,
    const float* __restrict__ Wq, const float* __restrict__ Wk,
    const float* __restrict__ Wv,
    unsigned short* __restrict__ Xqb, unsigned short* __restrict__ Xkb,
    unsigned short* __restrict__ Wqb, unsigned short* __restrict__ Wkb,
    unsigned short* __restrict__ Wvb)
{
    const int z = blockIdx.z;
    const float* src;
    unsigned short* dst;
    int n8;
    if (z == 0)      { src = query; dst = Xqb; n8 = 4096 * 512 / 8; }
    else if (z == 1) { src = key;   dst = Xkb; n8 = 4096 * 512 / 8; }
    else if (z == 2) { src = Wq;    dst = Wqb; n8 = 512 * 512 / 8;  }
    else if (z == 3) { src = Wk;    dst = Wkb; n8 = 512 * 512 / 8;  }
    else             { src = Wv;    dst = Wvb; n8 = 512 * 512 / 8;  }
    int idx = blockIdx.x * 256 + threadIdx.x;
    if (idx >= n8) return;
    const float4* s = (const float4*)src + (size_t)idx * 2;
    float4 a = s[0], b = s[1];
    uint4 o;
    o.x = cvt2(a.x, a.y); o.y = cvt2(a.z, a.w);
    o.z = cvt2(b.x, b.y); o.w = cvt2(b.z, b.w);
    *(uint4*)&dst[(size_t)idx * 8] = o;
}

// ---------------------------------------------------------------------------
// proj v5 = r8's v4 with grid dims SWAPPED for XCD co-location: grid
// (32 m-tiles, 8 c-tiles, 3 modes) -> bid = m + 32*c + 256*mode, so all 8
// c-blocks and all 3 modes sharing an m-slice have bid%8 = m%8 -> same XCD
// under round-robin dispatch -> X re-reads hit that XCD's L2 (working set
// ~2.5 MB < 4 MB) instead of streaming 96 MB from L3. K-loop unchanged.
// ---------------------------------------------------------------------------
#define XTILE (128 * 64)
#define WTILE (64 * 64)

__global__ __launch_bounds__(256) void proj_kernel(
    const unsigned short* __restrict__ Xqb, const unsigned short* __restrict__ Xkb,
    const unsigned short* __restrict__ Wqb, const unsigned short* __restrict__ Wkb,
    const unsigned short* __restrict__ Wvb, const float* __restrict__ coef,
    const float* __restrict__ posw, const float* __restrict__ posb,
    unsigned short* __restrict__ Af, unsigned short* __restrict__ Bf,
    unsigned short* __restrict__ Vf)
{
    const int mode = blockIdx.z;
    const int m0 = blockIdx.x * 128;   // 32 tiles (bid fastest dim -> XCD key)
    const int c0 = blockIdx.y * 64;    // 8 tiles
    const unsigned short* X = (mode == 0) ? Xqb : Xkb;
    const unsigned short* W = (mode == 0) ? Wqb : (mode == 1 ? Wkb : Wvb);

    __shared__ __align__(16) unsigned short smem[2 * XTILE + 2 * WTILE];  // 48 KB

    const int t = threadIdx.x;
    const int lane = t & 63, wv = t >> 6;
    const int lm = lane & 31, half = lane >> 5;
    const int wrow = wv >> 1, wcol = wv & 1;

    f32x16 acc[2] = {};

    auto stage = [&](int kt, int b) {
        int ko = kt * 64;
        unsigned short* xd = smem + b * XTILE;
        unsigned short* wd = smem + 2 * XTILE + b * WTILE;
#pragma unroll
        for (int it = 0; it < 4; ++it) {
            int cid = t + it * 256, row = cid >> 3, seg = cid & 7;
            const unsigned short* src =
                X + (size_t)(m0 + row) * 512 + ko + (((seg ^ (row & 7)) << 3));
            gload16(src, xd + cid * 8);
        }
#pragma unroll
        for (int it = 0; it < 2; ++it) {
            int cid = t + it * 256, row = cid >> 3, seg = cid & 7;
            const unsigned short* src =
                W + (size_t)(c0 + row) * 512 + ko + (((seg ^ (row & 7)) << 3));
            gload16(src, wd + cid * 8);
        }
    };

    stage(0, 0);
    const int rx = 64 * wrow + lm, rw = 32 * wcol + lm;
    for (int kt = 0; kt < 8; ++kt) {
        if (kt < 7) {
            stage(kt + 1, (kt + 1) & 1);
            asm volatile("s_waitcnt vmcnt(6)" ::: "memory");
        } else {
            asm volatile("s_waitcnt vmcnt(0)" ::: "memory");
        }
        __builtin_amdgcn_s_barrier();

        const unsigned short* xb = smem + (kt & 1) * XTILE;
        const unsigned short* wb = smem + 2 * XTILE + (kt & 1) * WTILE;
        __builtin_amdgcn_s_setprio(1);
#pragma unroll
        for (int ks = 0; ks < 4; ++ks) {
            int sA = (((half + 2 * ks) ^ (lm & 7)) << 3);
            bf16x8 a0 = *(const bf16x8*)&xb[rx * 64 + sA];
            bf16x8 a1 = *(const bf16x8*)&xb[(rx + 32) * 64 + sA];
            bf16x8 b  = *(const bf16x8*)&wb[rw * 64 + sA];
            acc[0] = __builtin_amdgcn_mfma_f32_32x32x16_bf16(a0, b, acc[0], 0, 0, 0);
            acc[1] = __builtin_amdgcn_mfma_f32_32x32x16_bf16(a1, b, acc[1], 0, 0, 0);
        }
        __builtin_amdgcn_s_setprio(0);
        asm volatile("s_waitcnt lgkmcnt(0)" ::: "memory");
        __builtin_amdgcn_sched_barrier(0);
        __builtin_amdgcn_s_barrier();
    }

    if (mode != 2) {
        unsigned short* Feat = (mode == 0) ? Af : Bf;
        int c = c0 + 32 * wcol + lm;
        int h = c >> 6, jj = c & 63;
        float wgt = posw[c];
        float bia = (mode == 0) ? posb[c] : 0.f;
        float cf  = (mode == 1) ? coef[c] : 1.f;
#pragma unroll
        for (int i = 0; i < 2; ++i)
#pragma unroll
        for (int r = 0; r < 16; ++r) {
            int rl = (r & 3) + 8 * (r >> 2) + 4 * half;
            int m = m0 + 64 * wrow + 32 * i + rl;
            int n = m >> 11, l = m & 2047;
            float ang = (float)l * wgt + bia;
            float sn, cs; __sincosf(ang, &sn, &cs);
            float v = softplusf(acc[i][r]) * cf;
            size_t base = ((size_t)(n * 8 + h) * 2048 + l) * 128 + jj;
            Feat[base]      = f2bfu(v * cs);
            Feat[base + 64] = f2bfu(v * sn);
        }
    } else {
        float* tb = (float*)smem;
        float* tbw = tb + wv * (32 * 34);
        __syncthreads();
#pragma unroll
        for (int i = 0; i < 2; ++i) {
#pragma unroll
            for (int r = 0; r < 16; ++r) {
                int rl = (r & 3) + 8 * (r >> 2) + 4 * half;
                tbw[lm * 34 + rl] = acc[i][r];
            }
            int mb = m0 + 64 * wrow + 32 * i;
            int n = mb >> 11, l0 = mb & 2047;
#pragma unroll
            for (int rep = 0; rep < 16; ++rep) {
                int cl = rep * 2 + half;
                float v = tbw[cl * 34 + lm];
                int c = c0 + 32 * wcol + cl;
                int h = c >> 6, dd = c & 63;
                Vf[((size_t)(n * 8 + h) * 64 + dd) * 2048 + l0 + lm] = f2bfu(v);
            }
        }
    }
}

// ---------------------------------------------------------------------------
// attn v4: fabric-BW attack. q-superblock of 128 rows (two 64-q tiles) share
// every staged K/V tile -> B/V re-read traffic HALVES (203->104 MB; attn ran
// at the 6.3 TB/s fabric ceiling post-T12, so bytes bind). Parity split-k
// (traffic-neutral) restores 512 blocks / 2-per-CU with complementary
// (j,15-j) pairing via bid+-256. Raw O-partials to out/opart, z to z0/z1;
// norm_kernel combines (r2-verified pattern). K/V LDS fragments are read
// ONCE and feed both q-tiles' MFMAs. Q-frags load directly from global.
// ---------------------------------------------------------------------------
__global__ __launch_bounds__(256) void attn_kernel(
    const unsigned short* __restrict__ Af, const unsigned short* __restrict__ Bf,
    const unsigned short* __restrict__ Vf, float* __restrict__ out,
    float* __restrict__ opart, float* __restrict__ z0, float* __restrict__ z1)
{
    const int bid = blockIdx.x;
    const int parity = bid >> 8;          // k-tile parity
    const int rr = bid & 255;
    const int nh = rr & 15;
    const int jraw = rr >> 4;             // 0..15
    const int j = parity ? (15 - jraw) : jraw;   // bid & bid+256 complementary
    const int q0 = j * 128;
    const int kmaxA = 2 * j;              // diagonal tile for q-tile A
    const int kmaxB = 2 * j + 1;          // diagonal tile for q-tile B

    __shared__ unsigned short Bs[64 * 136];   // K tile; O-merge overlay at end
    __shared__ unsigned short Vs[64 * 72];    // V [dd][k]
    __shared__ float zf[128];

    const int t = threadIdx.x;
    const int lane = t & 63, wv = t >> 6;
    const int lm = lane & 31, half = lane >> 5;
    const int qb = wv >> 1, kb = wv & 1;
    const int n = nh >> 3, h = nh & 7;

    const unsigned short* Ah = Af + (size_t)nh * 2048 * 128;
    const unsigned short* Bh = Bf + (size_t)nh * 2048 * 128;
    const unsigned short* Vh = Vf + (size_t)nh * 64 * 2048;

    // Q-fragments for both q-tiles, straight from global (B-operand rows = q)
    bf16x8 qfA[8], qfB[8];
    {
        const unsigned short* qra = &Ah[(size_t)(q0 + 32 * qb + lm) * 128 + half * 8];
        const unsigned short* qrb = qra + (size_t)64 * 128;
#pragma unroll
        for (int c = 0; c < 8; ++c) {
            qfA[c] = *(const bf16x8*)(qra + c * 16);
            qfB[c] = *(const bf16x8*)(qrb + c * 16);
        }
    }
    if (t < 128) zf[t] = 0.f;

    f32x16 oA0 = {}, oA1 = {}, oB0 = {}, oB1 = {};
    float zA = 0.f, zB = 0.f;

    u16x8 pb[4], pv[2];
    {
        const int k0 = parity * 64;
#pragma unroll
        for (int it = 0; it < 4; ++it) {
            int cid = t + it * 256, row = cid >> 4, off = (cid & 15) << 3;
            pb[it] = *(const u16x8*)&Bh[(size_t)(k0 + row) * 128 + off];
        }
#pragma unroll
        for (int it = 0; it < 2; ++it) {
            int cid = t + it * 256, row = cid >> 3, off = (cid & 7) << 3;
            pv[it] = *(const u16x8*)&Vh[(size_t)row * 2048 + k0 + off];
        }
    }

    for (int kt = parity; kt <= kmaxB; kt += 2) {
        __syncthreads();   // prev tile's LDS reads done (also orders zf init)
#pragma unroll
        for (int it = 0; it < 4; ++it) {
            int cid = t + it * 256, row = cid >> 4, off = (cid & 15) << 3;
            *(u16x8*)&Bs[row * 136 + off] = pb[it];
        }
#pragma unroll
        for (int it = 0; it < 2; ++it) {
            int cid = t + it * 256, row = cid >> 3, off = (cid & 7) << 3;
            *(u16x8*)&Vs[row * 72 + off] = pv[it];
        }
        __syncthreads();   // Bs/Vs visible
        if (kt + 2 <= kmaxB) {
            int k1 = (kt + 2) * 64;
#pragma unroll
            for (int it = 0; it < 4; ++it) {
                int cid = t + it * 256, row = cid >> 4, off = (cid & 15) << 3;
                pb[it] = *(const u16x8*)&Bh[(size_t)(k1 + row) * 128 + off];
            }
#pragma unroll
            for (int it = 0; it < 2; ++it) {
                int cid = t + it * 256, row = cid >> 3, off = (cid & 7) << 3;
                pv[it] = *(const u16x8*)&Vh[(size_t)row * 2048 + k1 + off];
            }
        }

        const bool doA = (kt <= kmaxA);   // block-uniform
        f32x16 sA = {}, sB = {};
        const unsigned short* kbase = &Bs[(32 * kb + lm) * 136 + half * 8];
        __builtin_amdgcn_s_setprio(1);
#pragma unroll
        for (int ks = 0; ks < 8; ++ks) {
            bf16x8 kf = *(const bf16x8*)(kbase + ks * 16);
            if (doA) sA = __builtin_amdgcn_mfma_f32_32x32x16_bf16(kf, qfA[ks], sA, 0, 0, 0);
            sB = __builtin_amdgcn_mfma_f32_32x32x16_bf16(kf, qfB[ks], sB, 0, 0, 0);
        }
        __builtin_amdgcn_s_setprio(0);

        // shared V fragments (read once for both q-tiles)
        const unsigned short* v0 = &Vs[(size_t)lm * 72 + 32 * kb + half * 8];
        const unsigned short* v1 = &Vs[(size_t)(32 + lm) * 72 + 32 * kb + half * 8];
        bf16x8 vb00 = *(const bf16x8*)(v0);
        bf16x8 vb10 = *(const bf16x8*)(v1);
        bf16x8 vb01 = *(const bf16x8*)(v0 + 16);
        bf16x8 vb11 = *(const bf16x8*)(v1 + 16);

        if (doA) {
            if (kt == kmaxA) {
#pragma unroll
                for (int r = 0; r < 16; ++r) {
                    int kl = (r & 3) + 8 * (r >> 2) + 4 * half;
                    if ((32 * kb + kl) > (32 * qb + lm)) sA[r] = 0.f;
                }
            }
#pragma unroll
            for (int r = 0; r < 16; ++r) zA += fabsf(sA[r]);
            union { u32x4 u; bf16x8 b; } pa0, pa1;
            {
                uint32_t A = pkbf(sA[0], sA[1]),  B = pkbf(sA[2], sA[3]);
                uint32_t C = pkbf(sA[4], sA[5]),  D = pkbf(sA[6], sA[7]);
                plswap(A, C); plswap(B, D);
                pa0.u = (u32x4){A, B, C, D};
                uint32_t E = pkbf(sA[8], sA[9]),  F = pkbf(sA[10], sA[11]);
                uint32_t G = pkbf(sA[12], sA[13]), H = pkbf(sA[14], sA[15]);
                plswap(E, G); plswap(F, H);
                pa1.u = (u32x4){E, F, G, H};
            }
            __builtin_amdgcn_s_setprio(1);
            oA0 = __builtin_amdgcn_mfma_f32_32x32x16_bf16(pa0.b, vb00, oA0, 0, 0, 0);
            oA1 = __builtin_amdgcn_mfma_f32_32x32x16_bf16(pa0.b, vb10, oA1, 0, 0, 0);
            oA0 = __builtin_amdgcn_mfma_f32_32x32x16_bf16(pa1.b, vb01, oA0, 0, 0, 0);
            oA1 = __builtin_amdgcn_mfma_f32_32x32x16_bf16(pa1.b, vb11, oA1, 0, 0, 0);
            __builtin_amdgcn_s_setprio(0);
        }
        {
            if (kt == kmaxB) {
#pragma unroll
                for (int r = 0; r < 16; ++r) {
                    int kl = (r & 3) + 8 * (r >> 2) + 4 * half;
                    if ((32 * kb + kl) > (32 * qb + lm)) sB[r] = 0.f;
                }
            }
#pragma unroll
            for (int r = 0; r < 16; ++r) zB += fabsf(sB[r]);
            union { u32x4 u; bf16x8 b; } pb0, pb1;
            {
                uint32_t A = pkbf(sB[0], sB[1]),  B = pkbf(sB[2], sB[3]);
                uint32_t C = pkbf(sB[4], sB[5]),  D = pkbf(sB[6], sB[7]);
                plswap(A, C); plswap(B, D);
                pb0.u = (u32x4){A, B, C, D};
                uint32_t E = pkbf(sB[8], sB[9]),  F = pkbf(sB[10], sB[11]);
                uint32_t G = pkbf(sB[12], sB[13]), H = pkbf(sB[14], sB[15]);
                plswap(E, G); plswap(F, H);
                pb1.u = (u32x4){E, F, G, H};
            }
            __builtin_amdgcn_s_setprio(1);
            oB0 = __builtin_amdgcn_mfma_f32_32x32x16_bf16(pb0.b, vb00, oB0, 0, 0, 0);
            oB1 = __builtin_amdgcn_mfma_f32_32x32x16_bf16(pb0.b, vb10, oB1, 0, 0, 0);
            oB0 = __builtin_amdgcn_mfma_f32_32x32x16_bf16(pb1.b, vb01, oB0, 0, 0, 0);
            oB1 = __builtin_amdgcn_mfma_f32_32x32x16_bf16(pb1.b, vb11, oB1, 0, 0, 0);
            __builtin_amdgcn_s_setprio(0);
        }
    }

    // z partials (q-tile A -> zf[0..63], B -> zf[64..127])
    atomicAdd(&zf[32 * qb + lm], zA);
    atomicAdd(&zf[64 + 32 * qb + lm], zB);
    __syncthreads();   // zf complete; last tile's LDS reads done -> overlay safe

    float* zdst = parity ? z1 : z0;
    if (t < 128) zdst[(size_t)nh * 2048 + q0 + t] = zf[t];

    float* dst = parity ? opart : out;
    float* Os = (float*)Bs;   // 64 x 65 f32 = 16640 B <= 17408 B
    // merge q-tile A across kb
    if (kb == 0) {
#pragma unroll
        for (int r = 0; r < 16; ++r) {
            int ql = (r & 3) + 8 * (r >> 2) + 4 * half;
            Os[(32 * qb + ql) * 65 + lm]      = oA0[r];
            Os[(32 * qb + ql) * 65 + 32 + lm] = oA1[r];
        }
    }
    __syncthreads();
    if (kb == 1) {
#pragma unroll
        for (int r = 0; r < 16; ++r) {
            int ql = (r & 3) + 8 * (r >> 2) + 4 * half;
            int q = q0 + 32 * qb + ql;
            size_t base = ((size_t)(n * 2048 + q)) * 512 + h * 64;
            dst[base + lm]      = Os[(32 * qb + ql) * 65 + lm]      + oA0[r];
            dst[base + 32 + lm] = Os[(32 * qb + ql) * 65 + 32 + lm] + oA1[r];
        }
    }
    __syncthreads();   // kb1 reads of Os-A done before Os-B overwrite
    // merge q-tile B
    if (kb == 0) {
#pragma unroll
        for (int r = 0; r < 16; ++r) {
            int ql = (r & 3) + 8 * (r >> 2) + 4 * half;
            Os[(32 * qb + ql) * 65 + lm]      = oB0[r];
            Os[(32 * qb + ql) * 65 + 32 + lm] = oB1[r];
        }
    }
    __syncthreads();
    if (kb == 1) {
#pragma unroll
        for (int r = 0; r < 16; ++r) {
            int ql = (r & 3) + 8 * (r >> 2) + 4 * half;
            int q = q0 + 64 + 32 * qb + ql;
            size_t base = ((size_t)(n * 2048 + q)) * 512 + h * 64;
            dst[base + lm]      = Os[(32 * qb + ql) * 65 + lm]      + oB0[r];
            dst[base + 32 + lm] = Os[(32 * qb + ql) * 65 + 32 + lm] + oB1[r];
        }
    }
}

// ---------------------------------------------------------------------------
// norm: out = (out_even + opart_odd) / (z0 + z1). r2-verified pattern.
// ---------------------------------------------------------------------------
__global__ __launch_bounds__(256) void norm_kernel(
    const float* __restrict__ opart, const float* __restrict__ z0,
    const float* __restrict__ z1, float* __restrict__ out)
{
    int idx = blockIdx.x * 256 + threadIdx.x;   // float4 index
    int i = idx << 2;
    int row = i >> 9;          // n*2048 + q
    int c = i & 511;
    int n = row >> 11, q = row & 2047;
    int h = c >> 6;
    size_t zi = (size_t)(n * 8 + h) * 2048 + q;
    float rz = 1.f / (z0[zi] + z1[zi]);
    float4 o = *(const float4*)&out[i];
    float4 pp = *(const float4*)&opart[i];
    float4 r;
    r.x = (o.x + pp.x) * rz;
    r.y = (o.y + pp.y) * rz;
    r.z = (o.z + pp.z) * rz;
    r.w = (o.w + pp.w) * rz;
    *(float4*)&out[i] = r;
}

extern "C" void kernel_launch(void* const* d_in, const int* in_sizes, int n_in,
                              void* d_out, int out_size, void* d_ws, size_t ws_size,
                              hipStream_t stream) {
    (void)in_sizes; (void)n_in; (void)out_size; (void)ws_size;
    const float* query = (const float*)d_in[0];
    const float* key   = (const float*)d_in[1];
    const float* Wq    = (const float*)d_in[2];
    const float* Wk    = (const float*)d_in[3];
    const float* Wv    = (const float*)d_in[4];
    const float* coef  = (const float*)d_in[5];
    const float* posw  = (const float*)d_in[6];
    const float* posb  = (const float*)d_in[7];

    unsigned short* Af  = (unsigned short*)d_ws;            // 8 MiB
    unsigned short* Bf  = Af + (size_t)16 * 2048 * 128;     // 8 MiB
    unsigned short* Vf  = Bf + (size_t)16 * 2048 * 128;     // 4 MiB
    unsigned short* Xqb = Vf + (size_t)16 * 64 * 2048;      // 4 MiB
    unsigned short* Xkb = Xqb + (size_t)4096 * 512;         // 4 MiB
    unsigned short* Wqb = Xkb + (size_t)4096 * 512;         // 0.5 MiB
    unsigned short* Wkb = Wqb + (size_t)512 * 512;          // 0.5 MiB
    unsigned short* Wvb = Wkb + (size_t)512 * 512;          // 0.5 MiB
    float* opart = (float*)(Wvb + (size_t)512 * 512);       // 8 MiB
    float* z0    = opart + (size_t)2 * 2048 * 512;          // 128 KiB
    float* z1    = z0 + (size_t)16 * 2048;                  // 128 KiB

    cvt_kernel<<<dim3(1024, 1, 5), 256, 0, stream>>>(
        query, key, Wq, Wk, Wv, Xqb, Xkb, Wqb, Wkb, Wvb);
    proj_kernel<<<dim3(32, 8, 3), 256, 0, stream>>>(
        Xqb, Xkb, Wqb, Wkb, Wvb, coef, posw, posb, Af, Bf, Vf);
    attn_kernel<<<dim3(512), 256, 0, stream>>>(
        Af, Bf, Vf, (float*)d_out, opart, z0, z1);
    norm_kernel<<<dim3(2048), 256, 0, stream>>>(
        opart, z0, z1, (float*)d_out);
}